// Round 17
// baseline (572.893 us; speedup 1.0000x reference)
//
#include <hip/hip_runtime.h>

typedef unsigned long long u64;

#define N1c 4096
#define N2c 49152
#define Dc 512
#define SPLITc 24576
#define NSPLITc 2
#define CAPc 65536
#define WPSc (SPLITc / 64)   /* 384 mask words per row per split */
#define SIM_Tc 0.2f
#define AMB_Tc 0.17f
#define CANDMAX (1 << 20)

typedef int i32x4 __attribute__((ext_vector_type(4)));

// ---------------------------------------------------------------- fill out=-1 (+ zero both split counters)
__global__ void sim_fill_out_k(int* __restrict__ out, int n, int* __restrict__ ccount) {
  int i = blockIdx.x * blockDim.x + threadIdx.x;
  if (i < n) out[i] = -1;
  if (i < NSPLITc) ccount[i] = 0;
}

// ---------------------------------------------------------------- normalize + int8 quantize (all rows)
// one wave per row. Emits: invn (for exact recheck), i8 row (|i|<=127), and
// qmeta[row] = {q, SL1=q*Sum|i|} for the per-pair provable error bound.
__global__ void sim_quant_k(const float* __restrict__ f1, const float* __restrict__ f2,
                            float* __restrict__ invn, signed char* __restrict__ f1q,
                            signed char* __restrict__ f2q, float2* __restrict__ qmeta) {
  int wid = threadIdx.x >> 6, lane = threadIdx.x & 63;
  int row = blockIdx.x * 4 + wid;
  if (row >= N1c + N2c) return;
  const float* src = (row < N1c) ? (f1 + (size_t)row * Dc)
                                 : (f2 + (size_t)(row - N1c) * Dc);
  const float4* p = (const float4*)src;
  float4 v0 = p[lane];
  float4 v1 = p[lane + 64];
  float ss = v0.x*v0.x + v0.y*v0.y + v0.z*v0.z + v0.w*v0.w
           + v1.x*v1.x + v1.y*v1.y + v1.z*v1.z + v1.w*v1.w;
  #pragma unroll
  for (int d = 1; d < 64; d <<= 1) ss += __shfl_xor(ss, d);
  float inv = 1.0f / fmaxf(sqrtf(ss), 1e-12f);
  float n[8] = {v0.x*inv, v0.y*inv, v0.z*inv, v0.w*inv,
                v1.x*inv, v1.y*inv, v1.z*inv, v1.w*inv};
  float m = 0.f;
  #pragma unroll
  for (int j = 0; j < 8; ++j) m = fmaxf(m, fabsf(n[j]));
  #pragma unroll
  for (int d = 1; d < 64; d <<= 1) m = fmaxf(m, __shfl_xor(m, d));
  float q  = fmaxf(m, 1e-30f) * (1.0f / 127.0f);
  float rq = 1.0f / q;
  int iq[8], l1 = 0;
  #pragma unroll
  for (int j = 0; j < 8; ++j) {
    int t = (int)rintf(n[j] * rq);
    t = max(-127, min(127, t));
    iq[j] = t; l1 += abs(t);
  }
  #pragma unroll
  for (int d = 1; d < 64; d <<= 1) l1 += __shfl_xor(l1, d);
  signed char* dst = (row < N1c) ? (f1q + (size_t)row * Dc)
                                 : (f2q + (size_t)(row - N1c) * Dc);
  char4 c0; c0.x = (signed char)iq[0]; c0.y = (signed char)iq[1];
            c0.z = (signed char)iq[2]; c0.w = (signed char)iq[3];
  char4 c1; c1.x = (signed char)iq[4]; c1.y = (signed char)iq[5];
            c1.z = (signed char)iq[6]; c1.w = (signed char)iq[7];
  ((char4*)dst)[lane]      = c0;
  ((char4*)dst)[lane + 64] = c1;
  if (lane == 0) { invn[row] = inv; qmeta[row] = make_float2(q, q * (float)l1); }
}

// ---------------------------------------------------------------- i8 MFMA GEMM + classify
// R16's proven structure at HALF the K-steps: 128x128 tile, BK=128 i8 (128 B
// rows -> LDS layout, XOR swizzle, staging addressing byte-identical to bf16
// BK=64), 4 waves (2x2), serial 2-barrier K-steps (4 instead of 8), T1 XCD
// column-chunk swizzle, meta-LDS epilogue. MFMA: i32_16x16x64_i8 (2x bf16
// rate -> same MFMA-cycles/K). acc is exact i32; classification uses the
// per-pair provable quantization bound as the recheck band.
__global__ __launch_bounds__(256, 2) void sim_mfma_k(
    const signed char* __restrict__ Aq, const signed char* __restrict__ Bq,
    const int* __restrict__ labels, const int* __restrict__ indexes,
    const int* __restrict__ labels_db, const int* __restrict__ indexes_db,
    const float2* __restrict__ qmeta,
    u64* __restrict__ msim, u64* __restrict__ mamb,
    unsigned* __restrict__ cands, int* __restrict__ ccount, int s)
{
  __shared__ __align__(16) signed char As[128 * 128];   // 16 KB
  __shared__ __align__(16) signed char Bs[128 * 128];   // 16 KB
  __shared__ u64 wS[128][2];                            // 2 KB
  __shared__ u64 wA[128][2];                            // 2 KB
  __shared__ int   meta[512];    // row lab/idx, col lab/idx (128 each)
  __shared__ float fmeta[512];   // row q, row SL1, col q, col SL1 (128 each)

  const int tid  = threadIdx.x;
  const int lane = tid & 63;
  const int wid  = tid >> 6;
  const int wm   = wid >> 1, wn = wid & 1;
  const int rbase = blockIdx.y * 128;
  // T1 bijective XCD chunk swizzle (192 = 8 * 24)
  const int bx   = blockIdx.x;
  const int cbase = ((bx & 7) * 24 + (bx >> 3)) * 128;   // column within split
  const int gcb   = s * SPLITc + cbase;

  // coalesced metadata preload (visible by epilogue's syncs)
  {
    int r0 = tid & 127;
    bool hi = tid >= 128;
    meta[tid]       = hi ? indexes[rbase + r0]  : labels[rbase + r0];
    meta[256 + tid] = hi ? indexes_db[gcb + r0] : labels_db[gcb + r0];
    if (!hi) {
      float2 mr = qmeta[rbase + r0];
      fmeta[r0] = mr.x; fmeta[128 + r0] = mr.y;
    } else {
      float2 mc = qmeta[N1c + gcb + r0];
      fmeta[256 + r0] = mc.x; fmeta[384 + r0] = mc.y;
    }
  }

  i32x4 acc[4][4];
  #pragma unroll
  for (int i = 0; i < 4; ++i)
    #pragma unroll
    for (int j = 0; j < 4; ++j) acc[i][j] = (i32x4){0, 0, 0, 0};

  for (int kb = 0; kb < Dc; kb += 128) {   // 4 K-steps of BK=128 i8
    __syncthreads();
    #pragma unroll
    for (int c4 = 0; c4 < 4; ++c4) {
      int c   = wid * 4 + c4;                 // chunk 0..15 (8 rows each)
      int row = c * 8 + (lane >> 3);
      int ls  = (lane & 7) ^ (row & 7);       // logical 16B-slot for phys slot
      const signed char* ga = Aq + (size_t)(rbase + row) * Dc + kb + ls * 16;
      const signed char* gb = Bq + (size_t)(gcb + row) * Dc + kb + ls * 16;
      __builtin_amdgcn_global_load_lds((const __attribute__((address_space(1))) void*)ga,
          (__attribute__((address_space(3))) void*)(As + c * 1024), 16, 0, 0);
      __builtin_amdgcn_global_load_lds((const __attribute__((address_space(1))) void*)gb,
          (__attribute__((address_space(3))) void*)(Bs + c * 1024), 16, 0, 0);
    }
    __syncthreads();   // compiler drains vmcnt before barrier
    #pragma unroll
    for (int kk = 0; kk < 2; ++kk) {         // two K=64 MFMA sub-steps
      i32x4 a[4], b[4];
      #pragma unroll
      for (int mi = 0; mi < 4; ++mi) {
        int r  = wm * 64 + mi * 16 + (lane & 15);
        int ps = (kk * 4 + (lane >> 4)) ^ (r & 7);
        a[mi] = *(const i32x4*)(const void*)(As + r * 128 + ps * 16);
      }
      #pragma unroll
      for (int ni = 0; ni < 4; ++ni) {
        int r  = wn * 64 + ni * 16 + (lane & 15);
        int ps = (kk * 4 + (lane >> 4)) ^ (r & 7);
        b[ni] = *(const i32x4*)(const void*)(Bs + r * 128 + ps * 16);
      }
      #pragma unroll
      for (int mi = 0; mi < 4; ++mi)
        #pragma unroll
        for (int ni = 0; ni < 4; ++ni)
          acc[mi][ni] = __builtin_amdgcn_mfma_i32_16x16x64_i8(a[mi], b[ni], acc[mi][ni], 0, 0, 0);
    }
  }

  // ---- classify (C layout: col=lane&15, row=(lane>>4)*4+reg) ----
  wS[tid >> 1][tid & 1] = 0;
  wA[tid >> 1][tid & 1] = 0;
  __syncthreads();

  int lab2[4], idx2[4], cloc[4]; float qb_[4], sb_[4];
  #pragma unroll
  for (int ni = 0; ni < 4; ++ni) {
    int cl = wn * 64 + ni * 16 + (lane & 15);   // 0..127 within tile
    cloc[ni] = cbase + cl;
    lab2[ni] = meta[256 + cl];
    idx2[ni] = meta[384 + cl];
    qb_[ni]  = fmeta[256 + cl];
    sb_[ni]  = fmeta[384 + cl];
  }

  #pragma unroll
  for (int mi = 0; mi < 4; ++mi) {
    #pragma unroll
    for (int r = 0; r < 4; ++r) {
      int row128 = wm * 64 + mi * 16 + (lane >> 4) * 4 + r;
      int gr = rbase + row128;
      int lab1 = meta[row128], idx1 = meta[128 + row128];
      float qa = fmeta[row128], sa = fmeta[128 + row128];
      u64 sb = 0, ab = 0;
      #pragma unroll
      for (int ni = 0; ni < 4; ++ni) {
        float v   = (float)acc[mi][ni][r] * (qa * qb_[ni]);
        float bnd = 0.5f * (qa * sb_[ni] + qb_[ni] * sa) + 128.f * (qa * qb_[ni]) + 1e-3f;
        if (idx1 < idx2[ni] && lab1 != lab2[ni]) {
          if (v > SIM_Tc + bnd) {
            sb |= 1ull << (ni * 16 + (lane & 15));
          } else if (v > AMB_Tc - bnd) {
            if (v < SIM_Tc - bnd && v > AMB_Tc + bnd) {
              ab |= 1ull << (ni * 16 + (lane & 15));
            } else {   // within the provable band of a threshold: exact recheck
              int ci = atomicAdd(ccount, 1);
              if (ci < CANDMAX)
                cands[ci] = ((unsigned)gr << 15) | (unsigned)cloc[ni];
            }
          }
        }
      }
      if (sb) atomicOr(&wS[row128][wn], sb);
      if (ab) atomicOr(&wA[row128][wn], ab);
    }
  }
  __syncthreads();
  {
    int row128 = tid >> 1, jh = tid & 1;
    size_t w = (size_t)(rbase + row128) * WPSc + (cbase >> 6) + jh;
    msim[w] = wS[row128][jh];
    mamb[w] = wA[row128][jh];
  }
}

// ---------------------------------------------------------------- exact f32 recheck of band pairs
__global__ void sim_recheck_k(const float* __restrict__ f1, const float* __restrict__ f2,
                              const float* __restrict__ invn,
                              const unsigned* __restrict__ cands, const int* __restrict__ ccount,
                              u64* __restrict__ msim, u64* __restrict__ mamb, int s) {
  int lane = threadIdx.x & 63;
  int gw = (blockIdx.x * blockDim.x + threadIdx.x) >> 6;
  int nw = (gridDim.x * blockDim.x) >> 6;
  int n = *ccount; if (n > CANDMAX) n = CANDMAX;
  for (int i = gw; i < n; i += nw) {
    unsigned pk = cands[i];
    int r = (int)(pk >> 15), c = (int)(pk & 0x7fffu);
    const float4* pa = (const float4*)(f1 + (size_t)r * Dc);
    const float4* pb = (const float4*)(f2 + ((size_t)s * SPLITc + c) * Dc);
    float4 a0 = pa[lane], a1 = pa[lane + 64];
    float4 b0 = pb[lane], b1 = pb[lane + 64];
    float d = a0.x*b0.x + a0.y*b0.y + a0.z*b0.z + a0.w*b0.w
            + a1.x*b1.x + a1.y*b1.y + a1.z*b1.z + a1.w*b1.w;
    #pragma unroll
    for (int t = 1; t < 64; t <<= 1) d += __shfl_xor(d, t);
    if (lane == 0) {
      float v = d * invn[r] * invn[N1c + s * SPLITc + c];
      if (v > SIM_Tc)
        atomicOr(&msim[(size_t)r * WPSc + (c >> 6)], 1ull << (c & 63));
      else if (v > AMB_Tc)
        atomicOr(&mamb[(size_t)r * WPSc + (c >> 6)], 1ull << (c & 63));
    }
  }
}

// ---------------------------------------------------------------- per-row counts
__global__ void sim_rowcount_k(const u64* __restrict__ msim, const u64* __restrict__ mamb,
                               int* __restrict__ rowcnt) {
  int row = blockIdx.x;
  int wid = threadIdx.x >> 6, lane = threadIdx.x & 63;
  const u64* m = wid ? mamb : msim;
  int ssum = 0;
  #pragma unroll
  for (int it = 0; it < WPSc / 64; ++it)
    ssum += __popcll(m[(size_t)row * WPSc + it * 64 + lane]);
  #pragma unroll
  for (int d = 32; d; d >>= 1) ssum += __shfl_down(ssum, d);
  if (lane == 0) rowcnt[wid * N1c + row] = ssum;
}

// ---------------------------------------------------------------- exclusive scan over 4096 rows
__global__ void sim_scan_k(const int* __restrict__ rowcnt, int* __restrict__ rowoff) {
  int cat = blockIdx.x;
  int tid = threadIdx.x;                  // 256 threads x 16 rows
  int v[16]; int ssum = 0;
  #pragma unroll
  for (int i = 0; i < 16; ++i) { v[i] = rowcnt[cat * N1c + tid * 16 + i]; ssum += v[i]; }
  int lane = tid & 63, wid = tid >> 6;
  int incl = ssum;
  #pragma unroll
  for (int d = 1; d < 64; d <<= 1) { int t = __shfl_up(incl, d); if (lane >= d) incl += t; }
  __shared__ int wsum[4];
  if (lane == 63) wsum[wid] = incl;
  __syncthreads();
  int woff = 0;
  for (int w = 0; w < wid; ++w) woff += wsum[w];
  int run = woff + incl - ssum;
  #pragma unroll
  for (int i = 0; i < 16; ++i) { rowoff[cat * N1c + tid * 16 + i] = run; run += v[i]; }
}

// ---------------------------------------------------------------- ordered scatter
__global__ void sim_scatter_k(const u64* __restrict__ msim, const u64* __restrict__ mamb,
                              const int* __restrict__ rowoff,
                              const int* __restrict__ labels, const int* __restrict__ counts,
                              const int* __restrict__ labels_db, const int* __restrict__ counts_db,
                              int* __restrict__ out, int s) {
  int row = blockIdx.x;
  int cat = blockIdx.y;
  int lane = threadIdx.x;
  const u64* m = cat ? mamb : msim;
  int* o = out + (cat ? (NSPLITc * CAPc * 2 + s * CAPc * 2) : (s * CAPc * 2));
  int run = rowoff[cat * N1c + row];
  int lab1 = labels[row];
  int cnt1 = counts[row];
  for (int it = 0; it < WPSc / 64; ++it) {
    int w = it * 64 + lane;
    u64 x = m[(size_t)row * WPSc + w];
    int pc = __popcll(x);
    int incl = pc;
    #pragma unroll
    for (int d = 1; d < 64; d <<= 1) { int t = __shfl_up(incl, d); if (lane >= d) incl += t; }
    int pos = run + incl - pc;
    int tot = __shfl(incl, 63);
    while (x) {
      int b = __builtin_ctzll(x);
      x &= x - 1;
      if (pos < CAPc) {
        int gc = s * SPLITc + w * 64 + b;
        int l2v = labels_db[gc];
        if (cat == 0) {
          o[2 * pos]     = lab1;
          o[2 * pos + 1] = l2v;
        } else {
          bool sw = cnt1 > counts_db[gc];
          o[2 * pos]     = sw ? l2v : lab1;
          o[2 * pos + 1] = sw ? lab1 : l2v;
        }
      }
      ++pos;
    }
    run += tot;
  }
}

// ---------------------------------------------------------------- launcher
extern "C" void kernel_launch(void* const* d_in, const int* in_sizes, int n_in,
                              void* d_out, int out_size, void* d_ws, size_t ws_size,
                              hipStream_t stream) {
  const float* features    = (const float*)d_in[0];
  const int*   labels      = (const int*)  d_in[1];
  const int*   counts      = (const int*)  d_in[2];
  const int*   indexes     = (const int*)  d_in[3];
  const float* features_db = (const float*)d_in[4];
  const int*   labels_db   = (const int*)  d_in[5];
  const int*   counts_db   = (const int*)  d_in[6];
  const int*   indexes_db  = (const int*)  d_in[7];
  int* out = (int*)d_out;

  // workspace layout (~57.2 MB)
  u64*   msim   = (u64*)d_ws;                           // 12.58 MB
  u64*   mamb   = msim + (size_t)N1c * WPSc;            // 12.58 MB
  float* invn   = (float*)(mamb + (size_t)N1c * WPSc);  // (N1+N2) f32
  int*   rowcnt = (int*)(invn + (N1c + N2c));           // [2][N1]
  int*   rowoff = rowcnt + 2 * N1c;                     // [2][N1]
  int*   ccount = rowoff + 2 * N1c;                     // [2] (+pad)
  unsigned* cands = (unsigned*)(ccount + 4);            // 4 MB
  float2* qmeta = (float2*)(cands + CANDMAX);           // (N1+N2)*8B = 0.43 MB
  signed char* f1q = (signed char*)(qmeta + (N1c + N2c));   // 2.1 MB
  signed char* f2q = f1q + (size_t)N1c * Dc;            // 25.2 MB (ALL db rows)

  sim_fill_out_k<<<(out_size + 255) / 256, 256, 0, stream>>>(out, out_size, ccount);
  sim_quant_k<<<(N1c + N2c + 3) / 4, 256, 0, stream>>>(features, features_db,
                                                       invn, f1q, f2q, qmeta);

  for (int s = 0; s < NSPLITc; ++s) {
    sim_mfma_k<<<dim3(SPLITc / 128, N1c / 128), 256, 0, stream>>>(
        f1q, f2q, labels, indexes, labels_db, indexes_db, qmeta,
        msim, mamb, cands, ccount + s, s);
    sim_recheck_k<<<512, 256, 0, stream>>>(features, features_db, invn,
                                           cands, ccount + s, msim, mamb, s);
    sim_rowcount_k<<<N1c, 128, 0, stream>>>(msim, mamb, rowcnt);
    sim_scan_k<<<2, 256, 0, stream>>>(rowcnt, rowoff);
    sim_scatter_k<<<dim3(N1c, 2), 64, 0, stream>>>(
        msim, mamb, rowoff, labels, counts, labels_db, counts_db, out, s);
  }
}

// Round 18
// 350.848 us; speedup vs baseline: 1.6329x; 1.6329x over previous
//
#include <hip/hip_runtime.h>

typedef unsigned long long u64;

#define N1c 4096
#define N2c 49152
#define Dc 512
#define SPLITc 24576
#define NSPLITc 2
#define CAPc 65536
#define WPSc (SPLITc / 64)   /* 384 mask words per row per split */
#define SIM_Tc 0.2f
#define AMB_Tc 0.17f
#define DELTAc 0.01f         /* bf16-vs-f32 safety band half-width (bound ~0.008) */
#define CANDMAX (1 << 20)

typedef __bf16 bf16x8 __attribute__((ext_vector_type(8)));
typedef float f32x4 __attribute__((ext_vector_type(4)));

static __device__ __forceinline__ unsigned short f2bf(float x) {
  unsigned u = __float_as_uint(x);
  unsigned r = (u + 0x7fffu + ((u >> 16) & 1u)) >> 16;   // RNE
  return (unsigned short)r;
}

// ---------------------------------------------------------------- fill out=-1 (+ zero counters)
__global__ void sim_fill_out_k(int* __restrict__ out, int n, int* __restrict__ ccount,
                               int* __restrict__ rowcnt) {
  int i = blockIdx.x * blockDim.x + threadIdx.x;
  if (i < n) out[i] = -1;
  if (i < NSPLITc) ccount[i] = 0;
  if (i < 2 * NSPLITc * N1c) rowcnt[i] = 0;   // [split][cat][N1]
}

// ---------------------------------------------------------------- norms (+ bf16 queries + split-0 db)
__global__ void sim_norm_k(const float* __restrict__ f1, const float* __restrict__ f2,
                           float* __restrict__ invn, unsigned short* __restrict__ f1nb,
                           unsigned short* __restrict__ f2nb) {
  int wid = threadIdx.x >> 6, lane = threadIdx.x & 63;
  int row = blockIdx.x * 4 + wid;
  if (row >= N1c + N2c) return;
  const float* src = (row < N1c) ? (f1 + (size_t)row * Dc)
                                 : (f2 + (size_t)(row - N1c) * Dc);
  const float4* p = (const float4*)src;
  float4 v0 = p[lane];
  float4 v1 = p[lane + 64];
  float ss = v0.x*v0.x + v0.y*v0.y + v0.z*v0.z + v0.w*v0.w
           + v1.x*v1.x + v1.y*v1.y + v1.z*v1.z + v1.w*v1.w;
  #pragma unroll
  for (int d = 1; d < 64; d <<= 1) ss += __shfl_xor(ss, d);
  float inv = 1.0f / fmaxf(sqrtf(ss), 1e-12f);
  if (lane == 0) invn[row] = inv;
  unsigned short* dst = 0;
  if (row < N1c) dst = f1nb + (size_t)row * Dc;
  else if (row < N1c + SPLITc) dst = f2nb + (size_t)(row - N1c) * Dc;
  if (dst) {
    ushort4 o0, o1;
    o0.x = f2bf(v0.x*inv); o0.y = f2bf(v0.y*inv); o0.z = f2bf(v0.z*inv); o0.w = f2bf(v0.w*inv);
    o1.x = f2bf(v1.x*inv); o1.y = f2bf(v1.y*inv); o1.z = f2bf(v1.z*inv); o1.w = f2bf(v1.w*inv);
    ushort4* q = (ushort4*)dst;
    q[lane] = o0; q[lane + 64] = o1;
  }
}

// ---------------------------------------------------------------- per-split db -> normalized bf16 (split 1 only)
__global__ void sim_conv2_k(const float* __restrict__ f2, const float* __restrict__ invn,
                            unsigned short* __restrict__ f2nb, int s) {
  int wid = threadIdx.x >> 6, lane = threadIdx.x & 63;
  int rloc = blockIdx.x * 4 + wid;
  if (rloc >= SPLITc) return;
  int grow = s * SPLITc + rloc;
  float inv = invn[N1c + grow];
  const float4* p = (const float4*)(f2 + (size_t)grow * Dc);
  float4 v0 = p[lane];
  float4 v1 = p[lane + 64];
  ushort4 o0, o1;
  o0.x = f2bf(v0.x*inv); o0.y = f2bf(v0.y*inv); o0.z = f2bf(v0.z*inv); o0.w = f2bf(v0.w*inv);
  o1.x = f2bf(v1.x*inv); o1.y = f2bf(v1.y*inv); o1.z = f2bf(v1.z*inv); o1.w = f2bf(v1.w*inv);
  ushort4* q = (ushort4*)(f2nb + (size_t)rloc * Dc);
  q[lane] = o0; q[lane + 64] = o1;
}

// ---------------------------------------------------------------- bf16 MFMA GEMM + classify
// R16 VERBATIM structure (proven best: 160 us/dispatch, MfmaUtil 28%):
// 128x128 tile, BK=64, 4 waves (2x2), serial 2-barrier K-steps, T1 XCD
// column-chunk swizzle, meta-LDS epilogue. Config sits exactly on the TLP
// cliff edge: 64 VGPR + 64 acc = 128 regs/wave (4 waves/SIMD) and 38 KB LDS
// (4 blocks/CU) -> 16 waves/CU. Do not perturb (R7-R17 falsified all moves).
// NEW (epilogue only): per-row popcounts atomicAdd'ed into rowcnt -> the
// standalone rowcount kernel (2 dispatches + 50 MB of mask re-reads) is gone.
__global__ __launch_bounds__(256, 2) void sim_mfma_k(
    const unsigned short* __restrict__ Abf, const unsigned short* __restrict__ Bbf,
    const int* __restrict__ labels, const int* __restrict__ indexes,
    const int* __restrict__ labels_db, const int* __restrict__ indexes_db,
    u64* __restrict__ msim, u64* __restrict__ mamb,
    unsigned* __restrict__ cands, int* __restrict__ ccount,
    int* __restrict__ rowcnt, int s)
{
  __shared__ unsigned short As[128 * 64];   // 16 KB, rows of 128B, slot-swizzled
  __shared__ unsigned short Bs[128 * 64];   // 16 KB
  __shared__ u64 wS[128][2];                // 2 KB
  __shared__ u64 wA[128][2];                // 2 KB
  __shared__ int meta[512];                 // 2 KB: [0:128) row lab, [128:256) row idx,
                                            //       [256:384) col lab, [384:512) col idx

  const int tid  = threadIdx.x;
  const int lane = tid & 63;
  const int wid  = tid >> 6;
  const int wm   = wid >> 1, wn = wid & 1;
  const int rbase = blockIdx.y * 128;
  // T1 bijective XCD chunk swizzle (192 = 8 * 24): each XCD owns 24 contiguous
  // column tiles -> 3.07 MB B working set, L2-resident across row sweeps.
  const int bx   = blockIdx.x;
  const int cbase = ((bx & 7) * 24 + (bx >> 3)) * 128;   // column within split

  // coalesced metadata preload (issued before K-loop; visible by epilogue's syncs)
  {
    int r0 = tid & 127;
    bool hi = tid >= 128;
    int gcb = s * SPLITc + cbase;
    meta[tid]       = hi ? indexes[rbase + r0]    : labels[rbase + r0];
    meta[256 + tid] = hi ? indexes_db[gcb + r0]   : labels_db[gcb + r0];
  }

  f32x4 acc[4][4];
  #pragma unroll
  for (int i = 0; i < 4; ++i)
    #pragma unroll
    for (int j = 0; j < 4; ++j) acc[i][j] = (f32x4){0.f, 0.f, 0.f, 0.f};

  for (int kb = 0; kb < Dc; kb += 64) {
    __syncthreads();
    #pragma unroll
    for (int c4 = 0; c4 < 4; ++c4) {
      int c   = wid * 4 + c4;                 // chunk 0..15 (8 rows each)
      int row = c * 8 + (lane >> 3);
      int ls  = (lane & 7) ^ (row & 7);       // logical k-slot for this phys slot
      const unsigned short* ga = Abf + (size_t)(rbase + row) * Dc + kb + ls * 8;
      const unsigned short* gb = Bbf + (size_t)(cbase + row) * Dc + kb + ls * 8;
      __builtin_amdgcn_global_load_lds((const __attribute__((address_space(1))) void*)ga,
          (__attribute__((address_space(3))) void*)(As + c * 512), 16, 0, 0);
      __builtin_amdgcn_global_load_lds((const __attribute__((address_space(1))) void*)gb,
          (__attribute__((address_space(3))) void*)(Bs + c * 512), 16, 0, 0);
    }
    __syncthreads();   // compiler drains vmcnt before barrier
    #pragma unroll
    for (int kk = 0; kk < 2; ++kk) {
      bf16x8 a[4], b[4];
      #pragma unroll
      for (int mi = 0; mi < 4; ++mi) {
        int r  = wm * 64 + mi * 16 + (lane & 15);
        int ps = (kk * 4 + (lane >> 4)) ^ (r & 7);
        a[mi] = *(const bf16x8*)(const void*)(As + r * 64 + ps * 8);
      }
      #pragma unroll
      for (int ni = 0; ni < 4; ++ni) {
        int r  = wn * 64 + ni * 16 + (lane & 15);
        int ps = (kk * 4 + (lane >> 4)) ^ (r & 7);
        b[ni] = *(const bf16x8*)(const void*)(Bs + r * 64 + ps * 8);
      }
      #pragma unroll
      for (int mi = 0; mi < 4; ++mi)
        #pragma unroll
        for (int ni = 0; ni < 4; ++ni)
          acc[mi][ni] = __builtin_amdgcn_mfma_f32_16x16x32_bf16(a[mi], b[ni], acc[mi][ni], 0, 0, 0);
    }
  }

  // ---- classify into bit masks (C layout: col=lane&15, row=(lane>>4)*4+reg) ----
  wS[tid >> 1][tid & 1] = 0;
  wA[tid >> 1][tid & 1] = 0;
  __syncthreads();

  int lab2[4], idx2[4], cloc[4];
  #pragma unroll
  for (int ni = 0; ni < 4; ++ni) {
    int cl = wn * 64 + ni * 16 + (lane & 15);   // 0..127 within tile
    cloc[ni] = cbase + cl;
    lab2[ni] = meta[256 + cl];
    idx2[ni] = meta[384 + cl];
  }

  #pragma unroll
  for (int mi = 0; mi < 4; ++mi) {
    #pragma unroll
    for (int r = 0; r < 4; ++r) {
      int row128 = wm * 64 + mi * 16 + (lane >> 4) * 4 + r;
      int gr = rbase + row128;
      int lab1 = meta[row128], idx1 = meta[128 + row128];
      u64 sb = 0, ab = 0;
      #pragma unroll
      for (int ni = 0; ni < 4; ++ni) {
        float v = acc[mi][ni][r];
        if (idx1 < idx2[ni] && lab1 != lab2[ni]) {
          if (v > SIM_Tc + DELTAc) {
            sb |= 1ull << (ni * 16 + (lane & 15));
          } else if (v > AMB_Tc - DELTAc) {
            if (v < SIM_Tc - DELTAc && v > AMB_Tc + DELTAc) {
              ab |= 1ull << (ni * 16 + (lane & 15));
            } else {   // within ±DELTA of a threshold: exact f32 recheck later
              int ci = atomicAdd(ccount, 1);
              if (ci < CANDMAX)
                cands[ci] = ((unsigned)gr << 15) | (unsigned)cloc[ni];
            }
          }
        }
      }
      if (sb) atomicOr(&wS[row128][wn], sb);
      if (ab) atomicOr(&wA[row128][wn], ab);
    }
  }
  __syncthreads();
  {
    int row128 = tid >> 1, jh = tid & 1;
    size_t w = (size_t)(rbase + row128) * WPSc + (cbase >> 6) + jh;
    msim[w] = wS[row128][jh];
    mamb[w] = wA[row128][jh];
    // fused per-row counts (replaces the standalone rowcount kernel)
    if (jh == 0) {
      int c0 = __popcll(wS[row128][0]) + __popcll(wS[row128][1]);
      int c1 = __popcll(wA[row128][0]) + __popcll(wA[row128][1]);
      if (c0) atomicAdd(&rowcnt[rbase + row128], c0);
      if (c1) atomicAdd(&rowcnt[N1c + rbase + row128], c1);
    }
  }
}

// ---------------------------------------------------------------- exact f32 recheck of band pairs
// also bumps rowcnt for each bit it sets (band pairs are unique, never pre-set)
__global__ void sim_recheck_k(const float* __restrict__ f1, const float* __restrict__ f2,
                              const float* __restrict__ invn,
                              const unsigned* __restrict__ cands, const int* __restrict__ ccount,
                              u64* __restrict__ msim, u64* __restrict__ mamb,
                              int* __restrict__ rowcnt, int s) {
  int lane = threadIdx.x & 63;
  int gw = (blockIdx.x * blockDim.x + threadIdx.x) >> 6;
  int nw = (gridDim.x * blockDim.x) >> 6;
  int n = *ccount; if (n > CANDMAX) n = CANDMAX;
  for (int i = gw; i < n; i += nw) {
    unsigned pk = cands[i];
    int r = (int)(pk >> 15), c = (int)(pk & 0x7fffu);
    const float4* pa = (const float4*)(f1 + (size_t)r * Dc);
    const float4* pb = (const float4*)(f2 + ((size_t)s * SPLITc + c) * Dc);
    float4 a0 = pa[lane], a1 = pa[lane + 64];
    float4 b0 = pb[lane], b1 = pb[lane + 64];
    float d = a0.x*b0.x + a0.y*b0.y + a0.z*b0.z + a0.w*b0.w
            + a1.x*b1.x + a1.y*b1.y + a1.z*b1.z + a1.w*b1.w;
    #pragma unroll
    for (int t = 1; t < 64; t <<= 1) d += __shfl_xor(d, t);
    if (lane == 0) {
      float v = d * invn[r] * invn[N1c + s * SPLITc + c];
      if (v > SIM_Tc) {
        atomicOr(&msim[(size_t)r * WPSc + (c >> 6)], 1ull << (c & 63));
        atomicAdd(&rowcnt[r], 1);
      } else if (v > AMB_Tc) {
        atomicOr(&mamb[(size_t)r * WPSc + (c >> 6)], 1ull << (c & 63));
        atomicAdd(&rowcnt[N1c + r], 1);
      }
    }
  }
}

// ---------------------------------------------------------------- exclusive scan over 4096 rows
__global__ void sim_scan_k(const int* __restrict__ rowcnt, int* __restrict__ rowoff) {
  int cat = blockIdx.x;
  int tid = threadIdx.x;                  // 256 threads x 16 rows
  int v[16]; int ssum = 0;
  #pragma unroll
  for (int i = 0; i < 16; ++i) { v[i] = rowcnt[cat * N1c + tid * 16 + i]; ssum += v[i]; }
  int lane = tid & 63, wid = tid >> 6;
  int incl = ssum;
  #pragma unroll
  for (int d = 1; d < 64; d <<= 1) { int t = __shfl_up(incl, d); if (lane >= d) incl += t; }
  __shared__ int wsum[4];
  if (lane == 63) wsum[wid] = incl;
  __syncthreads();
  int woff = 0;
  for (int w = 0; w < wid; ++w) woff += wsum[w];
  int run = woff + incl - ssum;
  #pragma unroll
  for (int i = 0; i < 16; ++i) { rowoff[cat * N1c + tid * 16 + i] = run; run += v[i]; }
}

// ---------------------------------------------------------------- ordered scatter
__global__ void sim_scatter_k(const u64* __restrict__ msim, const u64* __restrict__ mamb,
                              const int* __restrict__ rowoff,
                              const int* __restrict__ labels, const int* __restrict__ counts,
                              const int* __restrict__ labels_db, const int* __restrict__ counts_db,
                              int* __restrict__ out, int s) {
  int row = blockIdx.x;
  int cat = blockIdx.y;
  int lane = threadIdx.x;
  const u64* m = cat ? mamb : msim;
  int* o = out + (cat ? (NSPLITc * CAPc * 2 + s * CAPc * 2) : (s * CAPc * 2));
  int run = rowoff[cat * N1c + row];
  int lab1 = labels[row];
  int cnt1 = counts[row];
  for (int it = 0; it < WPSc / 64; ++it) {
    int w = it * 64 + lane;
    u64 x = m[(size_t)row * WPSc + w];
    int pc = __popcll(x);
    int incl = pc;
    #pragma unroll
    for (int d = 1; d < 64; d <<= 1) { int t = __shfl_up(incl, d); if (lane >= d) incl += t; }
    int pos = run + incl - pc;
    int tot = __shfl(incl, 63);
    while (x) {
      int b = __builtin_ctzll(x);
      x &= x - 1;
      if (pos < CAPc) {
        int gc = s * SPLITc + w * 64 + b;
        int l2v = labels_db[gc];
        if (cat == 0) {
          o[2 * pos]     = lab1;
          o[2 * pos + 1] = l2v;
        } else {
          bool sw = cnt1 > counts_db[gc];
          o[2 * pos]     = sw ? l2v : lab1;
          o[2 * pos + 1] = sw ? lab1 : l2v;
        }
      }
      ++pos;
    }
    run += tot;
  }
}

// ---------------------------------------------------------------- launcher
extern "C" void kernel_launch(void* const* d_in, const int* in_sizes, int n_in,
                              void* d_out, int out_size, void* d_ws, size_t ws_size,
                              hipStream_t stream) {
  const float* features    = (const float*)d_in[0];
  const int*   labels      = (const int*)  d_in[1];
  const int*   counts      = (const int*)  d_in[2];
  const int*   indexes     = (const int*)  d_in[3];
  const float* features_db = (const float*)d_in[4];
  const int*   labels_db   = (const int*)  d_in[5];
  const int*   counts_db   = (const int*)  d_in[6];
  const int*   indexes_db  = (const int*)  d_in[7];
  int* out = (int*)d_out;

  // workspace layout (~57.5 MB)
  u64*   msim   = (u64*)d_ws;                           // 12.58 MB
  u64*   mamb   = msim + (size_t)N1c * WPSc;            // 12.58 MB
  float* invn   = (float*)(mamb + (size_t)N1c * WPSc);  // (N1+N2) f32
  int*   rowcnt = (int*)(invn + (N1c + N2c));           // [2 splits][2 cats][N1]
  int*   rowoff = rowcnt + 2 * NSPLITc * N1c;           // [2][N1]
  int*   ccount = rowoff + 2 * N1c;                     // [2] (+pad)
  unsigned* cands = (unsigned*)(ccount + 4);            // 4 MB
  unsigned short* f1nb = (unsigned short*)(cands + CANDMAX);  // 4 MB
  unsigned short* f2nb = f1nb + (size_t)N1c * Dc;       // 24 MB (per split, reused)

  sim_fill_out_k<<<(out_size + 255) / 256, 256, 0, stream>>>(out, out_size, ccount, rowcnt);
  sim_norm_k<<<(N1c + N2c + 3) / 4, 256, 0, stream>>>(features, features_db, invn, f1nb, f2nb);

  for (int s = 0; s < NSPLITc; ++s) {
    if (s) sim_conv2_k<<<SPLITc / 4, 256, 0, stream>>>(features_db, invn, f2nb, s);
    sim_mfma_k<<<dim3(SPLITc / 128, N1c / 128), 256, 0, stream>>>(
        f1nb, f2nb, labels, indexes, labels_db, indexes_db,
        msim, mamb, cands, ccount + s, rowcnt + s * 2 * N1c, s);
    sim_recheck_k<<<512, 256, 0, stream>>>(features, features_db, invn,
                                           cands, ccount + s, msim, mamb,
                                           rowcnt + s * 2 * N1c, s);
    sim_scan_k<<<2, 256, 0, stream>>>(rowcnt + s * 2 * N1c, rowoff);
    sim_scatter_k<<<dim3(N1c, 2), 64, 0, stream>>>(
        msim, mamb, rowoff, labels, counts, labels_db, counts_db, out, s);
  }
}

// Round 19
// 349.391 us; speedup vs baseline: 1.6397x; 1.0042x over previous
//
#include <hip/hip_runtime.h>

typedef unsigned long long u64;

#define N1c 4096
#define N2c 49152
#define Dc 512
#define SPLITc 24576
#define NSPLITc 2
#define CAPc 65536
#define WPSc (SPLITc / 64)   /* 384 mask words per row per split */
#define SIM_Tc 0.2f
#define AMB_Tc 0.17f
#define DELTAc 0.01f         /* bf16-vs-f32 safety band half-width (bound ~0.008) */
#define CANDMAX (1 << 20)

typedef __bf16 bf16x8 __attribute__((ext_vector_type(8)));
typedef float f32x4 __attribute__((ext_vector_type(4)));

static __device__ __forceinline__ unsigned short f2bf(float x) {
  unsigned u = __float_as_uint(x);
  unsigned r = (u + 0x7fffu + ((u >> 16) & 1u)) >> 16;   // RNE
  return (unsigned short)r;
}

// ---------------------------------------------------------------- fill out=-1 (+ zero counters)
__global__ void sim_fill_out_k(int* __restrict__ out, int n, int* __restrict__ ccount,
                               int* __restrict__ rowcnt) {
  int i = blockIdx.x * blockDim.x + threadIdx.x;
  if (i < n) out[i] = -1;
  if (i < NSPLITc) ccount[i] = 0;
  if (i < 2 * NSPLITc * N1c) rowcnt[i] = 0;   // [split][cat][N1]
}

// ---------------------------------------------------------------- norms (+ bf16 queries + split-0 db)
__global__ void sim_norm_k(const float* __restrict__ f1, const float* __restrict__ f2,
                           float* __restrict__ invn, unsigned short* __restrict__ f1nb,
                           unsigned short* __restrict__ f2nb) {
  int wid = threadIdx.x >> 6, lane = threadIdx.x & 63;
  int row = blockIdx.x * 4 + wid;
  if (row >= N1c + N2c) return;
  const float* src = (row < N1c) ? (f1 + (size_t)row * Dc)
                                 : (f2 + (size_t)(row - N1c) * Dc);
  const float4* p = (const float4*)src;
  float4 v0 = p[lane];
  float4 v1 = p[lane + 64];
  float ss = v0.x*v0.x + v0.y*v0.y + v0.z*v0.z + v0.w*v0.w
           + v1.x*v1.x + v1.y*v1.y + v1.z*v1.z + v1.w*v1.w;
  #pragma unroll
  for (int d = 1; d < 64; d <<= 1) ss += __shfl_xor(ss, d);
  float inv = 1.0f / fmaxf(sqrtf(ss), 1e-12f);
  if (lane == 0) invn[row] = inv;
  unsigned short* dst = 0;
  if (row < N1c) dst = f1nb + (size_t)row * Dc;
  else if (row < N1c + SPLITc) dst = f2nb + (size_t)(row - N1c) * Dc;
  if (dst) {
    ushort4 o0, o1;
    o0.x = f2bf(v0.x*inv); o0.y = f2bf(v0.y*inv); o0.z = f2bf(v0.z*inv); o0.w = f2bf(v0.w*inv);
    o1.x = f2bf(v1.x*inv); o1.y = f2bf(v1.y*inv); o1.z = f2bf(v1.z*inv); o1.w = f2bf(v1.w*inv);
    ushort4* q = (ushort4*)dst;
    q[lane] = o0; q[lane + 64] = o1;
  }
}

// ---------------------------------------------------------------- per-split db -> normalized bf16 (split 1 only)
__global__ void sim_conv2_k(const float* __restrict__ f2, const float* __restrict__ invn,
                            unsigned short* __restrict__ f2nb, int s) {
  int wid = threadIdx.x >> 6, lane = threadIdx.x & 63;
  int rloc = blockIdx.x * 4 + wid;
  if (rloc >= SPLITc) return;
  int grow = s * SPLITc + rloc;
  float inv = invn[N1c + grow];
  const float4* p = (const float4*)(f2 + (size_t)grow * Dc);
  float4 v0 = p[lane];
  float4 v1 = p[lane + 64];
  ushort4 o0, o1;
  o0.x = f2bf(v0.x*inv); o0.y = f2bf(v0.y*inv); o0.z = f2bf(v0.z*inv); o0.w = f2bf(v0.w*inv);
  o1.x = f2bf(v1.x*inv); o1.y = f2bf(v1.y*inv); o1.z = f2bf(v1.z*inv); o1.w = f2bf(v1.w*inv);
  ushort4* q = (ushort4*)(f2nb + (size_t)rloc * Dc);
  q[lane] = o0; q[lane + 64] = o1;
}

// ---------------------------------------------------------------- bf16 MFMA GEMM + classify
// FINAL (R18, proven best: 160 us/dispatch, MfmaUtil 28%, 350.8 us total):
// 128x128 tile, BK=64, 4 waves (2x2), serial 2-barrier K-steps, T1 XCD
// column-chunk swizzle, meta-LDS epilogue, fused per-row popcounts.
// Plateau arithmetic (16K cyc/block): MFMA ~5.1K (32%), LDS-read ~6.1K (38%),
// VALU ~33% -- three pipes each ~1/3, imperfectly overlapped by the 2-barrier
// structure. TLP capped at 4 waves/SIMD (128 VGPR/wave incl. 64 acc); every
// pipeline variant that cost occupancy regressed (R7/8/10/11/13/15/17); R12
// proved launch-bounds squeezing spills. At K=512 (8 K-steps) deep pipelines
// never amortize. Do not perturb.
__global__ __launch_bounds__(256, 2) void sim_mfma_k(
    const unsigned short* __restrict__ Abf, const unsigned short* __restrict__ Bbf,
    const int* __restrict__ labels, const int* __restrict__ indexes,
    const int* __restrict__ labels_db, const int* __restrict__ indexes_db,
    u64* __restrict__ msim, u64* __restrict__ mamb,
    unsigned* __restrict__ cands, int* __restrict__ ccount,
    int* __restrict__ rowcnt, int s)
{
  __shared__ unsigned short As[128 * 64];   // 16 KB, rows of 128B, slot-swizzled
  __shared__ unsigned short Bs[128 * 64];   // 16 KB
  __shared__ u64 wS[128][2];                // 2 KB
  __shared__ u64 wA[128][2];                // 2 KB
  __shared__ int meta[512];                 // 2 KB: [0:128) row lab, [128:256) row idx,
                                            //       [256:384) col lab, [384:512) col idx

  const int tid  = threadIdx.x;
  const int lane = tid & 63;
  const int wid  = tid >> 6;
  const int wm   = wid >> 1, wn = wid & 1;
  const int rbase = blockIdx.y * 128;
  // T1 bijective XCD chunk swizzle (192 = 8 * 24): each XCD owns 24 contiguous
  // column tiles -> 3.07 MB B working set, L2-resident across row sweeps.
  const int bx   = blockIdx.x;
  const int cbase = ((bx & 7) * 24 + (bx >> 3)) * 128;   // column within split

  // coalesced metadata preload (issued before K-loop; visible by epilogue's syncs)
  {
    int r0 = tid & 127;
    bool hi = tid >= 128;
    int gcb = s * SPLITc + cbase;
    meta[tid]       = hi ? indexes[rbase + r0]    : labels[rbase + r0];
    meta[256 + tid] = hi ? indexes_db[gcb + r0]   : labels_db[gcb + r0];
  }

  f32x4 acc[4][4];
  #pragma unroll
  for (int i = 0; i < 4; ++i)
    #pragma unroll
    for (int j = 0; j < 4; ++j) acc[i][j] = (f32x4){0.f, 0.f, 0.f, 0.f};

  for (int kb = 0; kb < Dc; kb += 64) {
    __syncthreads();
    #pragma unroll
    for (int c4 = 0; c4 < 4; ++c4) {
      int c   = wid * 4 + c4;                 // chunk 0..15 (8 rows each)
      int row = c * 8 + (lane >> 3);
      int ls  = (lane & 7) ^ (row & 7);       // logical k-slot for this phys slot
      const unsigned short* ga = Abf + (size_t)(rbase + row) * Dc + kb + ls * 8;
      const unsigned short* gb = Bbf + (size_t)(cbase + row) * Dc + kb + ls * 8;
      __builtin_amdgcn_global_load_lds((const __attribute__((address_space(1))) void*)ga,
          (__attribute__((address_space(3))) void*)(As + c * 512), 16, 0, 0);
      __builtin_amdgcn_global_load_lds((const __attribute__((address_space(1))) void*)gb,
          (__attribute__((address_space(3))) void*)(Bs + c * 512), 16, 0, 0);
    }
    __syncthreads();   // compiler drains vmcnt before barrier
    #pragma unroll
    for (int kk = 0; kk < 2; ++kk) {
      bf16x8 a[4], b[4];
      #pragma unroll
      for (int mi = 0; mi < 4; ++mi) {
        int r  = wm * 64 + mi * 16 + (lane & 15);
        int ps = (kk * 4 + (lane >> 4)) ^ (r & 7);
        a[mi] = *(const bf16x8*)(const void*)(As + r * 64 + ps * 8);
      }
      #pragma unroll
      for (int ni = 0; ni < 4; ++ni) {
        int r  = wn * 64 + ni * 16 + (lane & 15);
        int ps = (kk * 4 + (lane >> 4)) ^ (r & 7);
        b[ni] = *(const bf16x8*)(const void*)(Bs + r * 64 + ps * 8);
      }
      #pragma unroll
      for (int mi = 0; mi < 4; ++mi)
        #pragma unroll
        for (int ni = 0; ni < 4; ++ni)
          acc[mi][ni] = __builtin_amdgcn_mfma_f32_16x16x32_bf16(a[mi], b[ni], acc[mi][ni], 0, 0, 0);
    }
  }

  // ---- classify into bit masks (C layout: col=lane&15, row=(lane>>4)*4+reg) ----
  wS[tid >> 1][tid & 1] = 0;
  wA[tid >> 1][tid & 1] = 0;
  __syncthreads();

  int lab2[4], idx2[4], cloc[4];
  #pragma unroll
  for (int ni = 0; ni < 4; ++ni) {
    int cl = wn * 64 + ni * 16 + (lane & 15);   // 0..127 within tile
    cloc[ni] = cbase + cl;
    lab2[ni] = meta[256 + cl];
    idx2[ni] = meta[384 + cl];
  }

  #pragma unroll
  for (int mi = 0; mi < 4; ++mi) {
    #pragma unroll
    for (int r = 0; r < 4; ++r) {
      int row128 = wm * 64 + mi * 16 + (lane >> 4) * 4 + r;
      int gr = rbase + row128;
      int lab1 = meta[row128], idx1 = meta[128 + row128];
      u64 sb = 0, ab = 0;
      #pragma unroll
      for (int ni = 0; ni < 4; ++ni) {
        float v = acc[mi][ni][r];
        if (idx1 < idx2[ni] && lab1 != lab2[ni]) {
          if (v > SIM_Tc + DELTAc) {
            sb |= 1ull << (ni * 16 + (lane & 15));
          } else if (v > AMB_Tc - DELTAc) {
            if (v < SIM_Tc - DELTAc && v > AMB_Tc + DELTAc) {
              ab |= 1ull << (ni * 16 + (lane & 15));
            } else {   // within ±DELTA of a threshold: exact f32 recheck later
              int ci = atomicAdd(ccount, 1);
              if (ci < CANDMAX)
                cands[ci] = ((unsigned)gr << 15) | (unsigned)cloc[ni];
            }
          }
        }
      }
      if (sb) atomicOr(&wS[row128][wn], sb);
      if (ab) atomicOr(&wA[row128][wn], ab);
    }
  }
  __syncthreads();
  {
    int row128 = tid >> 1, jh = tid & 1;
    size_t w = (size_t)(rbase + row128) * WPSc + (cbase >> 6) + jh;
    msim[w] = wS[row128][jh];
    mamb[w] = wA[row128][jh];
    // fused per-row counts (replaces the standalone rowcount kernel)
    if (jh == 0) {
      int c0 = __popcll(wS[row128][0]) + __popcll(wS[row128][1]);
      int c1 = __popcll(wA[row128][0]) + __popcll(wA[row128][1]);
      if (c0) atomicAdd(&rowcnt[rbase + row128], c0);
      if (c1) atomicAdd(&rowcnt[N1c + rbase + row128], c1);
    }
  }
}

// ---------------------------------------------------------------- exact f32 recheck of band pairs
// also bumps rowcnt for each bit it sets (band pairs are unique, never pre-set)
__global__ void sim_recheck_k(const float* __restrict__ f1, const float* __restrict__ f2,
                              const float* __restrict__ invn,
                              const unsigned* __restrict__ cands, const int* __restrict__ ccount,
                              u64* __restrict__ msim, u64* __restrict__ mamb,
                              int* __restrict__ rowcnt, int s) {
  int lane = threadIdx.x & 63;
  int gw = (blockIdx.x * blockDim.x + threadIdx.x) >> 6;
  int nw = (gridDim.x * blockDim.x) >> 6;
  int n = *ccount; if (n > CANDMAX) n = CANDMAX;
  for (int i = gw; i < n; i += nw) {
    unsigned pk = cands[i];
    int r = (int)(pk >> 15), c = (int)(pk & 0x7fffu);
    const float4* pa = (const float4*)(f1 + (size_t)r * Dc);
    const float4* pb = (const float4*)(f2 + ((size_t)s * SPLITc + c) * Dc);
    float4 a0 = pa[lane], a1 = pa[lane + 64];
    float4 b0 = pb[lane], b1 = pb[lane + 64];
    float d = a0.x*b0.x + a0.y*b0.y + a0.z*b0.z + a0.w*b0.w
            + a1.x*b1.x + a1.y*b1.y + a1.z*b1.z + a1.w*b1.w;
    #pragma unroll
    for (int t = 1; t < 64; t <<= 1) d += __shfl_xor(d, t);
    if (lane == 0) {
      float v = d * invn[r] * invn[N1c + s * SPLITc + c];
      if (v > SIM_Tc) {
        atomicOr(&msim[(size_t)r * WPSc + (c >> 6)], 1ull << (c & 63));
        atomicAdd(&rowcnt[r], 1);
      } else if (v > AMB_Tc) {
        atomicOr(&mamb[(size_t)r * WPSc + (c >> 6)], 1ull << (c & 63));
        atomicAdd(&rowcnt[N1c + r], 1);
      }
    }
  }
}

// ---------------------------------------------------------------- exclusive scan over 4096 rows
__global__ void sim_scan_k(const int* __restrict__ rowcnt, int* __restrict__ rowoff) {
  int cat = blockIdx.x;
  int tid = threadIdx.x;                  // 256 threads x 16 rows
  int v[16]; int ssum = 0;
  #pragma unroll
  for (int i = 0; i < 16; ++i) { v[i] = rowcnt[cat * N1c + tid * 16 + i]; ssum += v[i]; }
  int lane = tid & 63, wid = tid >> 6;
  int incl = ssum;
  #pragma unroll
  for (int d = 1; d < 64; d <<= 1) { int t = __shfl_up(incl, d); if (lane >= d) incl += t; }
  __shared__ int wsum[4];
  if (lane == 63) wsum[wid] = incl;
  __syncthreads();
  int woff = 0;
  for (int w = 0; w < wid; ++w) woff += wsum[w];
  int run = woff + incl - ssum;
  #pragma unroll
  for (int i = 0; i < 16; ++i) { rowoff[cat * N1c + tid * 16 + i] = run; run += v[i]; }
}

// ---------------------------------------------------------------- ordered scatter
__global__ void sim_scatter_k(const u64* __restrict__ msim, const u64* __restrict__ mamb,
                              const int* __restrict__ rowoff,
                              const int* __restrict__ labels, const int* __restrict__ counts,
                              const int* __restrict__ labels_db, const int* __restrict__ counts_db,
                              int* __restrict__ out, int s) {
  int row = blockIdx.x;
  int cat = blockIdx.y;
  int lane = threadIdx.x;
  const u64* m = cat ? mamb : msim;
  int* o = out + (cat ? (NSPLITc * CAPc * 2 + s * CAPc * 2) : (s * CAPc * 2));
  int run = rowoff[cat * N1c + row];
  int lab1 = labels[row];
  int cnt1 = counts[row];
  for (int it = 0; it < WPSc / 64; ++it) {
    int w = it * 64 + lane;
    u64 x = m[(size_t)row * WPSc + w];
    int pc = __popcll(x);
    int incl = pc;
    #pragma unroll
    for (int d = 1; d < 64; d <<= 1) { int t = __shfl_up(incl, d); if (lane >= d) incl += t; }
    int pos = run + incl - pc;
    int tot = __shfl(incl, 63);
    while (x) {
      int b = __builtin_ctzll(x);
      x &= x - 1;
      if (pos < CAPc) {
        int gc = s * SPLITc + w * 64 + b;
        int l2v = labels_db[gc];
        if (cat == 0) {
          o[2 * pos]     = lab1;
          o[2 * pos + 1] = l2v;
        } else {
          bool sw = cnt1 > counts_db[gc];
          o[2 * pos]     = sw ? l2v : lab1;
          o[2 * pos + 1] = sw ? lab1 : l2v;
        }
      }
      ++pos;
    }
    run += tot;
  }
}

// ---------------------------------------------------------------- launcher
extern "C" void kernel_launch(void* const* d_in, const int* in_sizes, int n_in,
                              void* d_out, int out_size, void* d_ws, size_t ws_size,
                              hipStream_t stream) {
  const float* features    = (const float*)d_in[0];
  const int*   labels      = (const int*)  d_in[1];
  const int*   counts      = (const int*)  d_in[2];
  const int*   indexes     = (const int*)  d_in[3];
  const float* features_db = (const float*)d_in[4];
  const int*   labels_db   = (const int*)  d_in[5];
  const int*   counts_db   = (const int*)  d_in[6];
  const int*   indexes_db  = (const int*)  d_in[7];
  int* out = (int*)d_out;

  // workspace layout (~57.5 MB)
  u64*   msim   = (u64*)d_ws;                           // 12.58 MB
  u64*   mamb   = msim + (size_t)N1c * WPSc;            // 12.58 MB
  float* invn   = (float*)(mamb + (size_t)N1c * WPSc);  // (N1+N2) f32
  int*   rowcnt = (int*)(invn + (N1c + N2c));           // [2 splits][2 cats][N1]
  int*   rowoff = rowcnt + 2 * NSPLITc * N1c;           // [2][N1]
  int*   ccount = rowoff + 2 * N1c;                     // [2] (+pad)
  unsigned* cands = (unsigned*)(ccount + 4);            // 4 MB
  unsigned short* f1nb = (unsigned short*)(cands + CANDMAX);  // 4 MB
  unsigned short* f2nb = f1nb + (size_t)N1c * Dc;       // 24 MB (per split, reused)

  sim_fill_out_k<<<(out_size + 255) / 256, 256, 0, stream>>>(out, out_size, ccount, rowcnt);
  sim_norm_k<<<(N1c + N2c + 3) / 4, 256, 0, stream>>>(features, features_db, invn, f1nb, f2nb);

  for (int s = 0; s < NSPLITc; ++s) {
    if (s) sim_conv2_k<<<SPLITc / 4, 256, 0, stream>>>(features_db, invn, f2nb, s);
    sim_mfma_k<<<dim3(SPLITc / 128, N1c / 128), 256, 0, stream>>>(
        f1nb, f2nb, labels, indexes, labels_db, indexes_db,
        msim, mamb, cands, ccount + s, rowcnt + s * 2 * N1c, s);
    sim_recheck_k<<<512, 256, 0, stream>>>(features, features_db, invn,
                                           cands, ccount + s, msim, mamb,
                                           rowcnt + s * 2 * N1c, s);
    sim_scan_k<<<2, 256, 0, stream>>>(rowcnt + s * 2 * N1c, rowoff);
    sim_scatter_k<<<dim3(N1c, 2), 64, 0, stream>>>(
        msim, mamb, rowoff, labels, counts, labels_db, counts_db, out, s);
  }
}